// Round 14
// baseline (175.682 us; speedup 1.0000x reference)
//
#include <hip/hip_runtime.h>
#include <hip/hip_bf16.h>
#include <cstdint>

typedef float f32x4 __attribute__((ext_vector_type(4)));
typedef __bf16 bf16x8 __attribute__((ext_vector_type(8)));

#define BS 128
#define NSP 196
#define NTM 32
#define DDIM 768

__device__ inline ushort4 f4_to_bf4(float4 v)
{
    ushort4 u;
    u.x = __builtin_bit_cast(unsigned short, (__bf16)v.x);
    u.y = __builtin_bit_cast(unsigned short, (__bf16)v.y);
    u.z = __builtin_bit_cast(unsigned short, (__bf16)v.z);
    u.w = __builtin_bit_cast(unsigned short, (__bf16)v.w);
    return u;
}

__device__ inline bf16x8 f4x2_to_bf8(float4 lo, float4 hi)
{
    bf16x8 r;
    r[0] = (__bf16)lo.x; r[1] = (__bf16)lo.y; r[2] = (__bf16)lo.z; r[3] = (__bf16)lo.w;
    r[4] = (__bf16)hi.x; r[5] = (__bf16)hi.y; r[6] = (__bf16)hi.z; r[7] = (__bf16)hi.w;
    return r;
}

__device__ inline float sumsq4(float4 a)
{
    return fmaf(a.x, a.x, fmaf(a.y, a.y, fmaf(a.z, a.z, a.w * a.w)));
}

// sum over the 16-lane DPP row; every lane gets the total.
__device__ inline float row16_sum(float x)
{
    int t;
    t = __builtin_amdgcn_update_dpp(0, __builtin_bit_cast(int, x), 0x121, 0xf, 0xf, true);
    x += __builtin_bit_cast(float, t);
    t = __builtin_amdgcn_update_dpp(0, __builtin_bit_cast(int, x), 0x122, 0xf, 0xf, true);
    x += __builtin_bit_cast(float, t);
    t = __builtin_amdgcn_update_dpp(0, __builtin_bit_cast(int, x), 0x124, 0xf, 0xf, true);
    x += __builtin_bit_cast(float, t);
    t = __builtin_amdgcn_update_dpp(0, __builtin_bit_cast(int, x), 0x128, 0xf, 0xf, true);
    x += __builtin_bit_cast(float, t);
    return x;
}

// ---------------- temporal row inverse-norms only ----------------
__global__ __launch_bounds__(256)
void tm_norm_kernel(const float* __restrict__ tm1, const float* __restrict__ tm2,
                    float* __restrict__ inx_tm, float* __restrict__ iny_tm)
{
    int B = blockIdx.x;
    const float* src; float* inv;
    if (B < 1024) { src = tm1; inv = inx_tm; }
    else          { B -= 1024; src = tm2; inv = iny_tm; }
    const int row  = B * 4 + (threadIdx.x >> 6);
    const int lane = threadIdx.x & 63;
    const float4* p = reinterpret_cast<const float4*>(src + (size_t)row * DDIM);
    float ss = 0.f;
#pragma unroll
    for (int c = 0; c < 3; ++c) ss += sumsq4(p[lane + 64 * c]);
#pragma unroll
    for (int off = 32; off; off >>= 1) ss += __shfl_xor(ss, off, 64);
    if (lane == 0) inv[row] = 1.0f / (sqrtf(ss) + 1e-12f);
}

// ========= spatial cost GEMM v3: A global->reg direct, B-only in LDS =========
// Grid 1024 = 8 XCD * 16 batch * 2 rowtile * 4 coltile. Block 256 thr (4 waves).
// A fragments (X[row][k0+q*8..+8]) load straight from L2 into registers ->
// cvt -> MFMA: no LDS round-trip, no barrier on the A path. B (64x64) staged
// bf16 in 16KB dbuf LDS, ONE barrier/K-tile. A-regs and B-regs pipelined one
// phase ahead with STATIC names (manual 2x unroll). Row norms fused.
__global__ __launch_bounds__(256, 3)
void cost_gemm_v3(const float* __restrict__ X, const float* __restrict__ Y,
                  __bf16* __restrict__ Aout)
{
    __shared__ __bf16 Bs0[4096];           // B buffer kt even
    __shared__ __bf16 Bs1[4096];           // B buffer kt odd
    __shared__ float  normA[128];
    __shared__ float  bnorm[64 * 4];

    const int flat  = blockIdx.x;
    const int xcd   = flat & 7;
    const int s     = flat >> 3;           // 0..127
    const int b     = xcd * 16 + (s >> 3);
    const int rem   = s & 7;
    const int rtile = rem >> 2;
    const int ct_   = rem & 3;
    const int n0    = (ct_ < 3) ? ct_ * 64 : 132;
    const int r0b   = rtile * 128;

    const int tid = threadIdx.x;
    const int w = tid >> 6, lane = tid & 63;
    const int q = lane >> 4, l16 = lane & 15;
    const int srow = tid >> 2;             // 0..63 (B staging row)
    const int scol = (tid & 3) * 16;       // 0,16,32,48

    const float* Yb = Y + ((size_t)b * NSP + n0) * DDIM;

    int arow[2];
#pragma unroll
    for (int rt = 0; rt < 2; ++rt) {
        int r = r0b + w * 32 + rt * 16 + l16;
        arow[rt] = b * NSP + min(r, NSP - 1);
    }

    float4 aF[2][2][2];     // [rt][ks][lo/hi] — all static indices
    bf16x8 af[2][2];        // converted fragments
    float4 B0[4], B1[4];
    float ssA[2] = {0.f, 0.f};
    float ssB = 0.f;

    auto loadA = [&](int kt) {
        int k0 = kt * 64 + q * 8;
#pragma unroll
        for (int rt = 0; rt < 2; ++rt) {
            const float* p = X + (size_t)arow[rt] * DDIM + k0;
#pragma unroll
            for (int ks = 0; ks < 2; ++ks) {
                aF[rt][ks][0] = *reinterpret_cast<const float4*>(p + ks * 32);
                aF[rt][ks][1] = *reinterpret_cast<const float4*>(p + ks * 32 + 4);
            }
        }
    };
    auto loadB = [&](float4 (&dst)[4], int kt) {
        const float* p = Yb + (size_t)srow * DDIM + kt * 64 + scol;
#pragma unroll
        for (int c = 0; c < 4; ++c) dst[c] = *reinterpret_cast<const float4*>(p + c * 4);
    };
    auto writeB = [&](__bf16* buf, float4 (&src)[4]) {
#pragma unroll
        for (int h = 0; h < 2; ++h) {
            int sl = (scol >> 3) + h;
            *reinterpret_cast<bf16x8*>(&buf[srow * 64 + ((sl ^ (srow & 7)) << 3)]) =
                f4x2_to_bf8(src[h * 2], src[h * 2 + 1]);
        }
        ssB += sumsq4(src[0]) + sumsq4(src[1]) + sumsq4(src[2]) + sumsq4(src[3]);
    };
    auto cvtA = [&]() {
#pragma unroll
        for (int rt = 0; rt < 2; ++rt) {
            float s4 = 0.f;
#pragma unroll
            for (int ks = 0; ks < 2; ++ks) {
                af[rt][ks] = f4x2_to_bf8(aF[rt][ks][0], aF[rt][ks][1]);
                s4 += sumsq4(aF[rt][ks][0]) + sumsq4(aF[rt][ks][1]);
            }
            ssA[rt] += s4;
        }
    };

    f32x4 acc[2][4];
#pragma unroll
    for (int i = 0; i < 2; ++i)
#pragma unroll
        for (int j = 0; j < 4; ++j) acc[i][j] = f32x4{0.f, 0.f, 0.f, 0.f};

    auto domfma = [&](const __bf16* buf) {
#pragma unroll
        for (int ks = 0; ks < 2; ++ks)
#pragma unroll
            for (int ct = 0; ct < 4; ++ct) {
                int r = ct * 16 + l16;
                bf16x8 bfr = *reinterpret_cast<const bf16x8*>(
                    &buf[r * 64 + (((ks * 4 + q) ^ (r & 7)) << 3)]);
#pragma unroll
                for (int rt = 0; rt < 2; ++rt)
                    acc[rt][ct] = __builtin_amdgcn_mfma_f32_16x16x32_bf16(af[rt][ks], bfr, acc[rt][ct], 0, 0, 0);
            }
    };

    // prologue
    loadA(0);
    loadB(B0, 0);
    loadB(B1, 1);
    writeB(Bs0, B0);                 // kt=0
    __syncthreads();

    for (int i = 0; i < 6; ++i) {
        int kt = 2 * i;
        // phase kt: compute Bs0, stage kt+1 into Bs1
        if (kt + 1 < 12) writeB(Bs1, B1);
        cvtA();                              // A(kt): loads issued one phase ago
        loadA(min(kt + 1, 11));
        loadB(B0, min(kt + 2, 11));
        domfma(Bs0);
        __syncthreads();
        // phase kt+1: compute Bs1, stage kt+2 into Bs0
        if (kt + 2 < 12) writeB(Bs0, B0);
        cvtA();                              // A(kt+1)
        loadA(min(kt + 2, 11));
        loadB(B1, min(kt + 3, 11));
        domfma(Bs1);
        __syncthreads();
    }

    // ---- norms: A rows via shfl over q, B rows via LDS partials ----
#pragma unroll
    for (int rt = 0; rt < 2; ++rt) {
        float v = ssA[rt];
        v += __shfl_xor(v, 16);
        v += __shfl_xor(v, 32);
        if (q == 0) normA[w * 32 + rt * 16 + l16] = v;
    }
    bnorm[srow * 4 + (tid & 3)] = ssB;
    __syncthreads();

    float ivy[4];
#pragma unroll
    for (int ct = 0; ct < 4; ++ct) {
        int jr = ct * 16 + l16;
        f32x4 t = *reinterpret_cast<const f32x4*>(&bnorm[jr * 4]);
        ivy[ct] = 1.0f / (sqrtf((t.x + t.y) + (t.z + t.w)) + 1e-12f);
    }
#pragma unroll
    for (int rt = 0; rt < 2; ++rt)
#pragma unroll
        for (int rr = 0; rr < 4; ++rr) {
            int li = w * 32 + rt * 16 + q * 4 + rr;
            int gi = r0b + li;
            if (gi < NSP) {
                float ivx = 1.0f / (sqrtf(normA[li]) + 1e-12f);
#pragma unroll
                for (int ct = 0; ct < 4; ++ct) {
                    float cs = acc[rt][ct][rr] * ivx * ivy[ct];
                    Aout[(size_t)b * 65536 + (size_t)gi * 256 + (n0 + ct * 16 + l16)] =
                        (__bf16)__expf(2.0f * cs - 2.0f);
                }
            }
        }
}

// ---------------- temporal cost GEMM (f32 in/out) ----------------
template<int WROWS, int NWAVES, int BN, int NPTS>
__global__ __launch_bounds__(NWAVES * 64)
void cost_gemm(const float* __restrict__ X, const float* __restrict__ Y,
               const float* __restrict__ invx, const float* __restrict__ invy,
               float* __restrict__ Aout)
{
    constexpr int MT = WROWS * NWAVES;
    constexpr int CT = BN / 16;
    constexpr int RT = WROWS / 16;
    constexpr int KP = 40;
    constexpr int NTH = NWAVES * 64;
    __shared__ __bf16 As[MT][KP];
    __shared__ __bf16 Bs[BN][KP];

    const int b    = blockIdx.y;
    const int row0 = blockIdx.x * MT;
    const int tid  = threadIdx.x;
    const int w    = tid >> 6, lane = tid & 63;
    const int q    = lane >> 4, l16 = lane & 15;
    const float* Xb = X + (size_t)b * NPTS * DDIM;
    const float* Yb = Y + (size_t)b * NPTS * DDIM;

    f32x4 acc[RT][CT];
#pragma unroll
    for (int i = 0; i < RT; ++i)
#pragma unroll
        for (int j = 0; j < CT; ++j) acc[i][j] = f32x4{0.f, 0.f, 0.f, 0.f};

    for (int k0 = 0; k0 < DDIM; k0 += 32) {
        __syncthreads();
        for (int idx = tid * 4; idx < MT * 32; idx += NTH * 4) {
            int r = idx >> 5, kk = idx & 31;
            int gr = row0 + r;
            float4 v = {0.f, 0.f, 0.f, 0.f};
            if (gr < NPTS) v = *reinterpret_cast<const float4*>(Xb + (size_t)gr * DDIM + k0 + kk);
            *reinterpret_cast<ushort4*>(&As[r][kk]) = f4_to_bf4(v);
        }
        for (int idx = tid * 4; idx < BN * 32; idx += NTH * 4) {
            int r = idx >> 5, kk = idx & 31;
            float4 v = {0.f, 0.f, 0.f, 0.f};
            if (r < NPTS) v = *reinterpret_cast<const float4*>(Yb + (size_t)r * DDIM + k0 + kk);
            *reinterpret_cast<ushort4*>(&Bs[r][kk]) = f4_to_bf4(v);
        }
        __syncthreads();

        bf16x8 af[RT];
#pragma unroll
        for (int rt = 0; rt < RT; ++rt)
            af[rt] = *reinterpret_cast<const bf16x8*>(&As[w * WROWS + rt * 16 + l16][q * 8]);
#pragma unroll
        for (int ct = 0; ct < CT; ++ct) {
            bf16x8 bfr = *reinterpret_cast<const bf16x8*>(&Bs[ct * 16 + l16][q * 8]);
#pragma unroll
            for (int rt = 0; rt < RT; ++rt)
                acc[rt][ct] = __builtin_amdgcn_mfma_f32_16x16x32_bf16(af[rt], bfr, acc[rt][ct], 0, 0, 0);
        }
    }

#pragma unroll
    for (int rt = 0; rt < RT; ++rt)
#pragma unroll
        for (int ct = 0; ct < CT; ++ct)
#pragma unroll
            for (int rr = 0; rr < 4; ++rr) {
                int i = row0 + w * WROWS + rt * 16 + q * 4 + rr;
                int j = ct * 16 + l16;
                if (i < NPTS && j < NPTS) {
                    float g  = acc[rt][ct][rr];
                    float cs = g * invx[b * NPTS + i] * invy[b * NPTS + j];
                    Aout[(size_t)b * NPTS * NPTS + (size_t)i * NPTS + j] = expf(-2.0f * (1.0f - cs));
                }
            }
}

// ========== fused IPOT v6: DPP rowsum, 512 thr, A in LDS ==========
__global__ __launch_bounds__(512, 1)
void ipot_dpp(const __bf16* __restrict__ Asp, const float* __restrict__ Atm,
              float* __restrict__ out)
{
    __shared__ __bf16 Alds[224 * 256];    // 114,688 B
    __shared__ float  cpart[32 * 260];    //  33,280 B
    __shared__ float  svec[2][272];
    __shared__ float  wsum[8];

    const int B = blockIdx.x;
    if (B >= 128) {
        if (threadIdx.x >= 64) return;
        const int b = B - 128;
        const float* Ab = Atm + (size_t)b * NTM * NTM;
        const int lane = threadIdx.x;
        const int rh = lane >> 5, cj = lane & 31;
        constexpr float MIU = 1.f / NTM;
        float A[16], P[16];
#pragma unroll
        for (int k = 0; k < 16; ++k) {
            A[k] = Ab[(rh + 2 * k) * NTM + cj];
            P[k] = 1.f;
        }
        float sv = MIU;
        for (int it = 0; it < 20; ++it) {
#pragma unroll
            for (int k = 0; k < 16; ++k) {
                P[k] *= A[k];
                float acc = row16_sum(P[k] * sv);
                acc += __shfl_xor(acc, 16);
                P[k] *= MIU * __builtin_amdgcn_rcpf(acc + 1e-6f);
            }
            float cssum = 0.f;
#pragma unroll
            for (int k = 0; k < 16; ++k) cssum += P[k];
            cssum += __shfl_xor(cssum, 32);
            float sg = MIU * __builtin_amdgcn_rcpf(cssum + 1e-6f);
#pragma unroll
            for (int k = 0; k < 16; ++k) P[k] *= sg;
            sv = sg;
        }
        float acc = 0.f;
#pragma unroll
        for (int k = 0; k < 16; ++k)
            acc = fmaf(P[k], -0.5f * __logf(A[k]), acc);
        acc = row16_sum(acc);
        acc += __shfl_xor(acc, 16);
        acc += __shfl_xor(acc, 32);
        if (lane == 0) atomicAdd(out, -acc * (1.f / BS));
        return;
    }

    const int b = (B & 7) * 16 + (B >> 3);
    const __bf16* Ab = Asp + (size_t)b * 65536;
    const int tid = threadIdx.x;
    const int w = tid >> 6, lane = tid & 63;
    const int rq = lane >> 4, cl = lane & 15;
    const int g = w * 4 + rq;
    const int colbase = cl * 8;
    constexpr float MIU = 1.f / NSP;

    for (int idx = tid; idx < NSP * 32; idx += 512) {
        int r = idx >> 5, c = idx & 31;
        bf16x8 v;
#pragma unroll
        for (int i = 0; i < 8; ++i) v[i] = (__bf16)0.f;
        if (c < 25) {
            v = *reinterpret_cast<const bf16x8*>(&Ab[(size_t)r * 256 + c * 8]);
            if (c == 24) { v[4] = (__bf16)0.f; v[5] = (__bf16)0.f; v[6] = (__bf16)0.f; v[7] = (__bf16)0.f; }
        }
        *reinterpret_cast<bf16x8*>(&Alds[r * 256 + c * 8]) = v;
    }
    {
        ushort4 z = {0, 0, 0, 0};
        for (int idx = tid; idx < 28 * 64; idx += 512) {
            int r = 196 + (idx >> 6), c4 = (idx & 63) << 2;
            *reinterpret_cast<ushort4*>(&Alds[r * 256 + c4]) = z;
        }
    }
    __syncthreads();

    float P[7][16];
#pragma unroll
    for (int k = 0; k < 7; ++k)
#pragma unroll
        for (int e = 0; e < 16; ++e) P[k][e] = 1.f;

    float sr[16];
#pragma unroll
    for (int e = 0; e < 16; ++e) {
        int j = (e < 8) ? (colbase + e) : (colbase + 128 + (e - 8));
        sr[e] = (j < NSP) ? MIU : 0.f;
    }

    for (int it = 0; it < 20; ++it) {
        float cs[16];
#pragma unroll
        for (int e = 0; e < 16; ++e) cs[e] = 0.f;

#pragma unroll
        for (int k = 0; k < 7; ++k) {
            const __bf16* ap = &Alds[(g + 32 * k) * 256 + colbase];
            bf16x8 a0 = *reinterpret_cast<const bf16x8*>(ap);
            bf16x8 a1 = *reinterpret_cast<const bf16x8*>(ap + 128);
            float r0 = 0.f, r1 = 0.f;
#pragma unroll
            for (int e = 0; e < 8; ++e) {
                P[k][e] *= (float)a0[e];
                r0 = fmaf(P[k][e], sr[e], r0);
            }
#pragma unroll
            for (int e = 0; e < 8; ++e) {
                P[k][8 + e] *= (float)a1[e];
                r1 = fmaf(P[k][8 + e], sr[8 + e], r1);
            }
            float racc = row16_sum(r0 + r1);
            float delta = MIU * __builtin_amdgcn_rcpf(racc + 1e-6f);
#pragma unroll
            for (int e = 0; e < 16; ++e) {
                P[k][e] *= delta;
                cs[e] += P[k][e];
            }
        }
        {
            float* cp = &cpart[g * 260 + colbase];
            *reinterpret_cast<f32x4*>(cp)     = f32x4{cs[0], cs[1], cs[2], cs[3]};
            *reinterpret_cast<f32x4*>(cp + 4) = f32x4{cs[4], cs[5], cs[6], cs[7]};
            float* cp2 = cp + 128;
            *reinterpret_cast<f32x4*>(cp2)     = f32x4{cs[8], cs[9], cs[10], cs[11]};
            *reinterpret_cast<f32x4*>(cp2 + 4) = f32x4{cs[12], cs[13], cs[14], cs[15]};
        }
        __syncthreads();
        if (tid < 256) {
            float s0 = 0.f, s1 = 0.f, s2 = 0.f, s3 = 0.f;
#pragma unroll
            for (int gg = 0; gg < 32; gg += 4) {
                s0 += cpart[(gg + 0) * 260 + tid];
                s1 += cpart[(gg + 1) * 260 + tid];
                s2 += cpart[(gg + 2) * 260 + tid];
                s3 += cpart[(gg + 3) * 260 + tid];
            }
            float sum = (s0 + s1) + (s2 + s3);
            svec[it & 1][tid] = (tid < NSP) ? (MIU * __builtin_amdgcn_rcpf(sum + 1e-6f)) : 0.f;
        }
        __syncthreads();
        {
            const float* sv = svec[it & 1];
            f32x4 t0 = *reinterpret_cast<const f32x4*>(&sv[colbase]);
            f32x4 t1 = *reinterpret_cast<const f32x4*>(&sv[colbase + 4]);
            f32x4 t2 = *reinterpret_cast<const f32x4*>(&sv[colbase + 128]);
            f32x4 t3 = *reinterpret_cast<const f32x4*>(&sv[colbase + 132]);
            sr[0] = t0.x; sr[1] = t0.y; sr[2] = t0.z; sr[3] = t0.w;
            sr[4] = t1.x; sr[5] = t1.y; sr[6] = t1.z; sr[7] = t1.w;
            sr[8] = t2.x; sr[9] = t2.y; sr[10] = t2.z; sr[11] = t2.w;
            sr[12] = t3.x; sr[13] = t3.y; sr[14] = t3.z; sr[15] = t3.w;
        }
#pragma unroll
        for (int k = 0; k < 7; ++k)
#pragma unroll
            for (int e = 0; e < 16; ++e) P[k][e] *= sr[e];
    }

    float acc = 0.f;
#pragma unroll
    for (int k = 0; k < 7; ++k) {
        const __bf16* ap = &Alds[(g + 32 * k) * 256 + colbase];
        bf16x8 a0 = *reinterpret_cast<const bf16x8*>(ap);
        bf16x8 a1 = *reinterpret_cast<const bf16x8*>(ap + 128);
#pragma unroll
        for (int e = 0; e < 8; ++e) {
            acc = fmaf(P[k][e],     -0.5f * __logf(fmaxf((float)a0[e], 1e-30f)), acc);
            acc = fmaf(P[k][8 + e], -0.5f * __logf(fmaxf((float)a1[e], 1e-30f)), acc);
        }
    }
    acc = row16_sum(acc);
    acc += __shfl_xor(acc, 16);
    acc += __shfl_xor(acc, 32);
    if (lane == 0) wsum[w] = acc;
    __syncthreads();
    if (tid == 0) {
        float t = 0.f;
#pragma unroll
        for (int i = 0; i < 8; ++i) t += wsum[i];
        atomicAdd(out, -t * (1.f / BS));
    }
}

extern "C" void kernel_launch(void* const* d_in, const int* in_sizes, int n_in,
                              void* d_out, int out_size, void* d_ws, size_t ws_size,
                              hipStream_t stream)
{
    const float* sp1 = (const float*)d_in[0];
    const float* sp2 = (const float*)d_in[1];
    const float* tm1 = (const float*)d_in[2];
    const float* tm2 = (const float*)d_in[3];
    float* out = (float*)d_out;
    float* ws  = (float*)d_ws;

    float* inx_tm = ws;                          // 4096
    float* iny_tm = inx_tm + BS * NTM;           // 4096
    float* A_tm   = iny_tm + BS * NTM;           // 131072 f32
    __bf16* A_sp  = (__bf16*)(ws + 139264);      // 128*256*256 bf16 = 33,554,432 B

    tm_norm_kernel<<<dim3(2048), 256, 0, stream>>>(tm1, tm2, inx_tm, iny_tm);

    cost_gemm_v3<<<dim3(1024), 256, 0, stream>>>(sp1, sp2, A_sp);

    cost_gemm<16, 2, 32, NTM><<<dim3(1, BS), 128, 0, stream>>>(tm1, tm2, inx_tm, iny_tm, A_tm);

    (void)hipMemsetAsync(d_out, 0, sizeof(float), stream);

    ipot_dpp<<<dim3(256), 512, 0, stream>>>(A_sp, A_tm, out);
}

// Round 15
// 153.460 us; speedup vs baseline: 1.1448x; 1.1448x over previous
//
#include <hip/hip_runtime.h>
#include <hip/hip_bf16.h>
#include <cstdint>

typedef float f32x4 __attribute__((ext_vector_type(4)));
typedef __bf16 bf16x8 __attribute__((ext_vector_type(8)));

#define BS 128
#define NSP 196
#define NTM 32
#define DDIM 768

__device__ inline ushort4 f4_to_bf4(float4 v)
{
    ushort4 u;
    u.x = __builtin_bit_cast(unsigned short, (__bf16)v.x);
    u.y = __builtin_bit_cast(unsigned short, (__bf16)v.y);
    u.z = __builtin_bit_cast(unsigned short, (__bf16)v.z);
    u.w = __builtin_bit_cast(unsigned short, (__bf16)v.w);
    return u;
}

__device__ inline bf16x8 f4x2_to_bf8(float4 lo, float4 hi)
{
    bf16x8 r;
    r[0] = (__bf16)lo.x; r[1] = (__bf16)lo.y; r[2] = (__bf16)lo.z; r[3] = (__bf16)lo.w;
    r[4] = (__bf16)hi.x; r[5] = (__bf16)hi.y; r[6] = (__bf16)hi.z; r[7] = (__bf16)hi.w;
    return r;
}

__device__ inline float sumsq4(float4 a)
{
    return fmaf(a.x, a.x, fmaf(a.y, a.y, fmaf(a.z, a.z, a.w * a.w)));
}

// sum over the 16-lane DPP row; every lane gets the total.
__device__ inline float row16_sum(float x)
{
    int t;
    t = __builtin_amdgcn_update_dpp(0, __builtin_bit_cast(int, x), 0x121, 0xf, 0xf, true);
    x += __builtin_bit_cast(float, t);
    t = __builtin_amdgcn_update_dpp(0, __builtin_bit_cast(int, x), 0x122, 0xf, 0xf, true);
    x += __builtin_bit_cast(float, t);
    t = __builtin_amdgcn_update_dpp(0, __builtin_bit_cast(int, x), 0x124, 0xf, 0xf, true);
    x += __builtin_bit_cast(float, t);
    t = __builtin_amdgcn_update_dpp(0, __builtin_bit_cast(int, x), 0x128, 0xf, 0xf, true);
    x += __builtin_bit_cast(float, t);
    return x;
}

// ---------------- temporal row inverse-norms only ----------------
__global__ __launch_bounds__(256)
void tm_norm_kernel(const float* __restrict__ tm1, const float* __restrict__ tm2,
                    float* __restrict__ inx_tm, float* __restrict__ iny_tm)
{
    int B = blockIdx.x;
    const float* src; float* inv;
    if (B < 1024) { src = tm1; inv = inx_tm; }
    else          { B -= 1024; src = tm2; inv = iny_tm; }
    const int row  = B * 4 + (threadIdx.x >> 6);
    const int lane = threadIdx.x & 63;
    const float4* p = reinterpret_cast<const float4*>(src + (size_t)row * DDIM);
    float ss = 0.f;
#pragma unroll
    for (int c = 0; c < 3; ++c) ss += sumsq4(p[lane + 64 * c]);
#pragma unroll
    for (int off = 32; off; off >>= 1) ss += __shfl_xor(ss, off, 64);
    if (lane == 0) inv[row] = 1.0f / (sqrtf(ss) + 1e-12f);
}

// ============== spatial cost GEMM, f32 inputs + fused row norms ==============
// Grid 512 = 8 XCD * 16 batch * 4 coltile. Block 448 thr (7 waves).
// Tile 224x64, BK=64. R15: SINGLE LDS buffer (36.9KB) — same 2 barriers/K-tile
// as the dbuf version, but 4 blocks/CU (28 waves) instead of 2 (14): doubles
// the latency-hiding pool that R11-R14 counters showed we lack.
#define GA_LDS 18432
__global__ __launch_bounds__(448)
void cost_gemm_spf(const float* __restrict__ X, const float* __restrict__ Y,
                   __bf16* __restrict__ Aout)
{
    __shared__ __bf16 lds[GA_LDS];         // 36,864 B
    float* ldsF = reinterpret_cast<float*>(lds);

    const int flat  = blockIdx.x;
    const int xcd   = flat & 7;
    const int s     = flat >> 3;
    const int b     = xcd * 16 + (s >> 2);
    const int ctile = s & 3;
    const int n0    = (ctile < 3) ? ctile * 64 : 132;

    const int tid  = threadIdx.x;
    const int w    = tid >> 6, lane = tid & 63;
    const int q    = lane >> 4, l16 = lane & 15;
    const int srow = tid >> 3;          // 0..55
    const int sslt = tid & 7;           // 0..7

    const float* Yb = Y + (size_t)b * NSP * DDIM;

    float4 aL[4], aH[4], bL, bH, b2L, b2H;
    float ssA[4] = {0.f, 0.f, 0.f, 0.f};
    float ssB = 0.f, ssB2 = 0.f;

    auto LOADS = [&](int k0) {
#pragma unroll
        for (int p = 0; p < 4; ++p) {
            int gr = b * NSP + srow + 56 * p;
            gr = min(gr, BS * NSP - 1);
            const float* sp = X + (size_t)gr * DDIM + k0 + sslt * 8;
            aL[p] = *reinterpret_cast<const float4*>(sp);
            aH[p] = *reinterpret_cast<const float4*>(sp + 4);
        }
        {
            const float* sp = Yb + (size_t)(n0 + srow) * DDIM + k0 + sslt * 8;
            bL = *reinterpret_cast<const float4*>(sp);
            bH = *reinterpret_cast<const float4*>(sp + 4);
        }
        if (tid < 64) {
            const float* sp = Yb + (size_t)(n0 + 56 + srow) * DDIM + k0 + sslt * 8;
            b2L = *reinterpret_cast<const float4*>(sp);
            b2H = *reinterpret_cast<const float4*>(sp + 4);
        }
    };
    auto WRITES = [&]() {
#pragma unroll
        for (int p = 0; p < 4; ++p) {
            int r = srow + 56 * p;
            ssA[p] += sumsq4(aL[p]) + sumsq4(aH[p]);
            *reinterpret_cast<bf16x8*>(&lds[r * 64 + ((sslt ^ (r & 7)) << 3)]) =
                f4x2_to_bf8(aL[p], aH[p]);
        }
        {
            int r = srow;
            ssB += sumsq4(bL) + sumsq4(bH);
            *reinterpret_cast<bf16x8*>(&lds[14336 + r * 64 + ((sslt ^ (r & 7)) << 3)]) =
                f4x2_to_bf8(bL, bH);
        }
        if (tid < 64) {
            int r = 56 + srow;
            ssB2 += sumsq4(b2L) + sumsq4(b2H);
            *reinterpret_cast<bf16x8*>(&lds[14336 + r * 64 + ((sslt ^ (r & 7)) << 3)]) =
                f4x2_to_bf8(b2L, b2H);
        }
    };

    f32x4 acc[2][4];
#pragma unroll
    for (int i = 0; i < 2; ++i)
#pragma unroll
        for (int j = 0; j < 4; ++j) acc[i][j] = f32x4{0.f, 0.f, 0.f, 0.f};

    LOADS(0);
    for (int kt = 0; kt < 12; ++kt) {
        if (kt) __syncthreads();             // prev tile fully consumed
        WRITES();
        __syncthreads();
        if (kt < 11) LOADS((kt + 1) * 64);   // covered by MFMA phase below
#pragma unroll
        for (int ks = 0; ks < 2; ++ks) {
            bf16x8 af[2], bf[4];
#pragma unroll
            for (int rt = 0; rt < 2; ++rt) {
                int r = w * 32 + rt * 16 + l16;
                af[rt] = *reinterpret_cast<const bf16x8*>(
                    &lds[r * 64 + (((ks * 4 + q) ^ (r & 7)) << 3)]);
            }
#pragma unroll
            for (int ct = 0; ct < 4; ++ct) {
                int r = ct * 16 + l16;
                bf[ct] = *reinterpret_cast<const bf16x8*>(
                    &lds[14336 + r * 64 + (((ks * 4 + q) ^ (r & 7)) << 3)]);
            }
#pragma unroll
            for (int ct = 0; ct < 4; ++ct)
#pragma unroll
                for (int rt = 0; rt < 2; ++rt)
                    acc[rt][ct] = __builtin_amdgcn_mfma_f32_16x16x32_bf16(af[rt], bf[ct], acc[rt][ct], 0, 0, 0);
        }
    }
    __syncthreads();

    // ---- reduce norm partials through the (now free) LDS buffer ----
#pragma unroll
    for (int p = 0; p < 4; ++p) ldsF[(srow + 56 * p) * 8 + sslt] = ssA[p];
    ldsF[1792 + srow * 8 + sslt] = ssB;
    if (tid < 64) ldsF[1792 + (56 + srow) * 8 + sslt] = ssB2;
    __syncthreads();

    float ivy[4];
#pragma unroll
    for (int ct = 0; ct < 4; ++ct) {
        int jr = ct * 16 + l16;
        f32x4 s0 = *reinterpret_cast<const f32x4*>(&ldsF[1792 + jr * 8]);
        f32x4 s1 = *reinterpret_cast<const f32x4*>(&ldsF[1792 + jr * 8 + 4]);
        float ss = (s0.x + s0.y) + (s0.z + s0.w) + (s1.x + s1.y) + (s1.z + s1.w);
        ivy[ct] = 1.0f / (sqrtf(ss) + 1e-12f);
    }
#pragma unroll
    for (int rt = 0; rt < 2; ++rt)
#pragma unroll
        for (int rr = 0; rr < 4; ++rr) {
            int i = w * 32 + rt * 16 + q * 4 + rr;
            if (i < NSP) {
                f32x4 s0 = *reinterpret_cast<const f32x4*>(&ldsF[i * 8]);
                f32x4 s1 = *reinterpret_cast<const f32x4*>(&ldsF[i * 8 + 4]);
                float ss = (s0.x + s0.y) + (s0.z + s0.w) + (s1.x + s1.y) + (s1.z + s1.w);
                float ivx = 1.0f / (sqrtf(ss) + 1e-12f);
#pragma unroll
                for (int ct = 0; ct < 4; ++ct) {
                    float cs = acc[rt][ct][rr] * ivx * ivy[ct];
                    Aout[(size_t)b * 65536 + (size_t)i * 256 + (n0 + ct * 16 + l16)] =
                        (__bf16)__expf(2.0f * cs - 2.0f);
                }
            }
        }
}

// ---------------- temporal cost GEMM (f32 in/out) ----------------
template<int WROWS, int NWAVES, int BN, int NPTS>
__global__ __launch_bounds__(NWAVES * 64)
void cost_gemm(const float* __restrict__ X, const float* __restrict__ Y,
               const float* __restrict__ invx, const float* __restrict__ invy,
               float* __restrict__ Aout)
{
    constexpr int MT = WROWS * NWAVES;
    constexpr int CT = BN / 16;
    constexpr int RT = WROWS / 16;
    constexpr int KP = 40;
    constexpr int NTH = NWAVES * 64;
    __shared__ __bf16 As[MT][KP];
    __shared__ __bf16 Bs[BN][KP];

    const int b    = blockIdx.y;
    const int row0 = blockIdx.x * MT;
    const int tid  = threadIdx.x;
    const int w    = tid >> 6, lane = tid & 63;
    const int q    = lane >> 4, l16 = lane & 15;
    const float* Xb = X + (size_t)b * NPTS * DDIM;
    const float* Yb = Y + (size_t)b * NPTS * DDIM;

    f32x4 acc[RT][CT];
#pragma unroll
    for (int i = 0; i < RT; ++i)
#pragma unroll
        for (int j = 0; j < CT; ++j) acc[i][j] = f32x4{0.f, 0.f, 0.f, 0.f};

    for (int k0 = 0; k0 < DDIM; k0 += 32) {
        __syncthreads();
        for (int idx = tid * 4; idx < MT * 32; idx += NTH * 4) {
            int r = idx >> 5, kk = idx & 31;
            int gr = row0 + r;
            float4 v = {0.f, 0.f, 0.f, 0.f};
            if (gr < NPTS) v = *reinterpret_cast<const float4*>(Xb + (size_t)gr * DDIM + k0 + kk);
            *reinterpret_cast<ushort4*>(&As[r][kk]) = f4_to_bf4(v);
        }
        for (int idx = tid * 4; idx < BN * 32; idx += NTH * 4) {
            int r = idx >> 5, kk = idx & 31;
            float4 v = {0.f, 0.f, 0.f, 0.f};
            if (r < NPTS) v = *reinterpret_cast<const float4*>(Yb + (size_t)r * DDIM + k0 + kk);
            *reinterpret_cast<ushort4*>(&Bs[r][kk]) = f4_to_bf4(v);
        }
        __syncthreads();

        bf16x8 af[RT];
#pragma unroll
        for (int rt = 0; rt < RT; ++rt)
            af[rt] = *reinterpret_cast<const bf16x8*>(&As[w * WROWS + rt * 16 + l16][q * 8]);
#pragma unroll
        for (int ct = 0; ct < CT; ++ct) {
            bf16x8 bfr = *reinterpret_cast<const bf16x8*>(&Bs[ct * 16 + l16][q * 8]);
#pragma unroll
            for (int rt = 0; rt < RT; ++rt)
                acc[rt][ct] = __builtin_amdgcn_mfma_f32_16x16x32_bf16(af[rt], bfr, acc[rt][ct], 0, 0, 0);
        }
    }

#pragma unroll
    for (int rt = 0; rt < RT; ++rt)
#pragma unroll
        for (int ct = 0; ct < CT; ++ct)
#pragma unroll
            for (int rr = 0; rr < 4; ++rr) {
                int i = row0 + w * WROWS + rt * 16 + q * 4 + rr;
                int j = ct * 16 + l16;
                if (i < NPTS && j < NPTS) {
                    float g  = acc[rt][ct][rr];
                    float cs = g * invx[b * NPTS + i] * invy[b * NPTS + j];
                    Aout[(size_t)b * NPTS * NPTS + (size_t)i * NPTS + j] = expf(-2.0f * (1.0f - cs));
                }
            }
}

// ========== fused IPOT v6: DPP rowsum, 512 thr, A in LDS ==========
__global__ __launch_bounds__(512, 1)
void ipot_dpp(const __bf16* __restrict__ Asp, const float* __restrict__ Atm,
              float* __restrict__ out)
{
    __shared__ __bf16 Alds[224 * 256];    // 114,688 B
    __shared__ float  cpart[32 * 260];    //  33,280 B
    __shared__ float  svec[2][272];
    __shared__ float  wsum[8];

    const int B = blockIdx.x;
    if (B >= 128) {
        if (threadIdx.x >= 64) return;
        const int b = B - 128;
        const float* Ab = Atm + (size_t)b * NTM * NTM;
        const int lane = threadIdx.x;
        const int rh = lane >> 5, cj = lane & 31;
        constexpr float MIU = 1.f / NTM;
        float A[16], P[16];
#pragma unroll
        for (int k = 0; k < 16; ++k) {
            A[k] = Ab[(rh + 2 * k) * NTM + cj];
            P[k] = 1.f;
        }
        float sv = MIU;
        for (int it = 0; it < 20; ++it) {
#pragma unroll
            for (int k = 0; k < 16; ++k) {
                P[k] *= A[k];
                float acc = row16_sum(P[k] * sv);
                acc += __shfl_xor(acc, 16);
                P[k] *= MIU * __builtin_amdgcn_rcpf(acc + 1e-6f);
            }
            float cssum = 0.f;
#pragma unroll
            for (int k = 0; k < 16; ++k) cssum += P[k];
            cssum += __shfl_xor(cssum, 32);
            float sg = MIU * __builtin_amdgcn_rcpf(cssum + 1e-6f);
#pragma unroll
            for (int k = 0; k < 16; ++k) P[k] *= sg;
            sv = sg;
        }
        float acc = 0.f;
#pragma unroll
        for (int k = 0; k < 16; ++k)
            acc = fmaf(P[k], -0.5f * __logf(A[k]), acc);
        acc = row16_sum(acc);
        acc += __shfl_xor(acc, 16);
        acc += __shfl_xor(acc, 32);
        if (lane == 0) atomicAdd(out, -acc * (1.f / BS));
        return;
    }

    const int b = (B & 7) * 16 + (B >> 3);
    const __bf16* Ab = Asp + (size_t)b * 65536;
    const int tid = threadIdx.x;
    const int w = tid >> 6, lane = tid & 63;
    const int rq = lane >> 4, cl = lane & 15;
    const int g = w * 4 + rq;
    const int colbase = cl * 8;
    constexpr float MIU = 1.f / NSP;

    for (int idx = tid; idx < NSP * 32; idx += 512) {
        int r = idx >> 5, c = idx & 31;
        bf16x8 v;
#pragma unroll
        for (int i = 0; i < 8; ++i) v[i] = (__bf16)0.f;
        if (c < 25) {
            v = *reinterpret_cast<const bf16x8*>(&Ab[(size_t)r * 256 + c * 8]);
            if (c == 24) { v[4] = (__bf16)0.f; v[5] = (__bf16)0.f; v[6] = (__bf16)0.f; v[7] = (__bf16)0.f; }
        }
        *reinterpret_cast<bf16x8*>(&Alds[r * 256 + c * 8]) = v;
    }
    {
        ushort4 z = {0, 0, 0, 0};
        for (int idx = tid; idx < 28 * 64; idx += 512) {
            int r = 196 + (idx >> 6), c4 = (idx & 63) << 2;
            *reinterpret_cast<ushort4*>(&Alds[r * 256 + c4]) = z;
        }
    }
    __syncthreads();

    float P[7][16];
#pragma unroll
    for (int k = 0; k < 7; ++k)
#pragma unroll
        for (int e = 0; e < 16; ++e) P[k][e] = 1.f;

    float sr[16];
#pragma unroll
    for (int e = 0; e < 16; ++e) {
        int j = (e < 8) ? (colbase + e) : (colbase + 128 + (e - 8));
        sr[e] = (j < NSP) ? MIU : 0.f;
    }

    for (int it = 0; it < 20; ++it) {
        float cs[16];
#pragma unroll
        for (int e = 0; e < 16; ++e) cs[e] = 0.f;

#pragma unroll
        for (int k = 0; k < 7; ++k) {
            const __bf16* ap = &Alds[(g + 32 * k) * 256 + colbase];
            bf16x8 a0 = *reinterpret_cast<const bf16x8*>(ap);
            bf16x8 a1 = *reinterpret_cast<const bf16x8*>(ap + 128);
            float r0 = 0.f, r1 = 0.f;
#pragma unroll
            for (int e = 0; e < 8; ++e) {
                P[k][e] *= (float)a0[e];
                r0 = fmaf(P[k][e], sr[e], r0);
            }
#pragma unroll
            for (int e = 0; e < 8; ++e) {
                P[k][8 + e] *= (float)a1[e];
                r1 = fmaf(P[k][8 + e], sr[8 + e], r1);
            }
            float racc = row16_sum(r0 + r1);
            float delta = MIU * __builtin_amdgcn_rcpf(racc + 1e-6f);
#pragma unroll
            for (int e = 0; e < 16; ++e) {
                P[k][e] *= delta;
                cs[e] += P[k][e];
            }
        }
        {
            float* cp = &cpart[g * 260 + colbase];
            *reinterpret_cast<f32x4*>(cp)     = f32x4{cs[0], cs[1], cs[2], cs[3]};
            *reinterpret_cast<f32x4*>(cp + 4) = f32x4{cs[4], cs[5], cs[6], cs[7]};
            float* cp2 = cp + 128;
            *reinterpret_cast<f32x4*>(cp2)     = f32x4{cs[8], cs[9], cs[10], cs[11]};
            *reinterpret_cast<f32x4*>(cp2 + 4) = f32x4{cs[12], cs[13], cs[14], cs[15]};
        }
        __syncthreads();
        if (tid < 256) {
            float s0 = 0.f, s1 = 0.f, s2 = 0.f, s3 = 0.f;
#pragma unroll
            for (int gg = 0; gg < 32; gg += 4) {
                s0 += cpart[(gg + 0) * 260 + tid];
                s1 += cpart[(gg + 1) * 260 + tid];
                s2 += cpart[(gg + 2) * 260 + tid];
                s3 += cpart[(gg + 3) * 260 + tid];
            }
            float sum = (s0 + s1) + (s2 + s3);
            svec[it & 1][tid] = (tid < NSP) ? (MIU * __builtin_amdgcn_rcpf(sum + 1e-6f)) : 0.f;
        }
        __syncthreads();
        {
            const float* sv = svec[it & 1];
            f32x4 t0 = *reinterpret_cast<const f32x4*>(&sv[colbase]);
            f32x4 t1 = *reinterpret_cast<const f32x4*>(&sv[colbase + 4]);
            f32x4 t2 = *reinterpret_cast<const f32x4*>(&sv[colbase + 128]);
            f32x4 t3 = *reinterpret_cast<const f32x4*>(&sv[colbase + 132]);
            sr[0] = t0.x; sr[1] = t0.y; sr[2] = t0.z; sr[3] = t0.w;
            sr[4] = t1.x; sr[5] = t1.y; sr[6] = t1.z; sr[7] = t1.w;
            sr[8] = t2.x; sr[9] = t2.y; sr[10] = t2.z; sr[11] = t2.w;
            sr[12] = t3.x; sr[13] = t3.y; sr[14] = t3.z; sr[15] = t3.w;
        }
#pragma unroll
        for (int k = 0; k < 7; ++k)
#pragma unroll
            for (int e = 0; e < 16; ++e) P[k][e] *= sr[e];
    }

    float acc = 0.f;
#pragma unroll
    for (int k = 0; k < 7; ++k) {
        const __bf16* ap = &Alds[(g + 32 * k) * 256 + colbase];
        bf16x8 a0 = *reinterpret_cast<const bf16x8*>(ap);
        bf16x8 a1 = *reinterpret_cast<const bf16x8*>(ap + 128);
#pragma unroll
        for (int e = 0; e < 8; ++e) {
            acc = fmaf(P[k][e],     -0.5f * __logf(fmaxf((float)a0[e], 1e-30f)), acc);
            acc = fmaf(P[k][8 + e], -0.5f * __logf(fmaxf((float)a1[e], 1e-30f)), acc);
        }
    }
    acc = row16_sum(acc);
    acc += __shfl_xor(acc, 16);
    acc += __shfl_xor(acc, 32);
    if (lane == 0) wsum[w] = acc;
    __syncthreads();
    if (tid == 0) {
        float t = 0.f;
#pragma unroll
        for (int i = 0; i < 8; ++i) t += wsum[i];
        atomicAdd(out, -t * (1.f / BS));
    }
}

extern "C" void kernel_launch(void* const* d_in, const int* in_sizes, int n_in,
                              void* d_out, int out_size, void* d_ws, size_t ws_size,
                              hipStream_t stream)
{
    const float* sp1 = (const float*)d_in[0];
    const float* sp2 = (const float*)d_in[1];
    const float* tm1 = (const float*)d_in[2];
    const float* tm2 = (const float*)d_in[3];
    float* out = (float*)d_out;
    float* ws  = (float*)d_ws;

    float* inx_tm = ws;                          // 4096
    float* iny_tm = inx_tm + BS * NTM;           // 4096
    float* A_tm   = iny_tm + BS * NTM;           // 131072 f32
    __bf16* A_sp  = (__bf16*)(ws + 139264);      // 128*256*256 bf16 = 33,554,432 B

    tm_norm_kernel<<<dim3(2048), 256, 0, stream>>>(tm1, tm2, inx_tm, iny_tm);

    cost_gemm_spf<<<dim3(512), 448, 0, stream>>>(sp1, sp2, A_sp);

    cost_gemm<16, 2, 32, NTM><<<dim3(1, BS), 128, 0, stream>>>(tm1, tm2, inx_tm, iny_tm, A_tm);

    (void)hipMemsetAsync(d_out, 0, sizeof(float), stream);

    ipot_dpp<<<dim3(256), 512, 0, stream>>>(A_sp, A_tm, out);
}

// Round 16
// 146.983 us; speedup vs baseline: 1.1953x; 1.0441x over previous
//
#include <hip/hip_runtime.h>
#include <hip/hip_bf16.h>
#include <cstdint>

typedef float f32x4 __attribute__((ext_vector_type(4)));
typedef __bf16 bf16x8 __attribute__((ext_vector_type(8)));

#define BS 128
#define NSP 196
#define NTM 32
#define DDIM 768

__device__ inline ushort4 f4_to_bf4(float4 v)
{
    ushort4 u;
    u.x = __builtin_bit_cast(unsigned short, (__bf16)v.x);
    u.y = __builtin_bit_cast(unsigned short, (__bf16)v.y);
    u.z = __builtin_bit_cast(unsigned short, (__bf16)v.z);
    u.w = __builtin_bit_cast(unsigned short, (__bf16)v.w);
    return u;
}

__device__ inline bf16x8 f4x2_to_bf8(float4 lo, float4 hi)
{
    bf16x8 r;
    r[0] = (__bf16)lo.x; r[1] = (__bf16)lo.y; r[2] = (__bf16)lo.z; r[3] = (__bf16)lo.w;
    r[4] = (__bf16)hi.x; r[5] = (__bf16)hi.y; r[6] = (__bf16)hi.z; r[7] = (__bf16)hi.w;
    return r;
}

__device__ inline float sumsq4(float4 a)
{
    return fmaf(a.x, a.x, fmaf(a.y, a.y, fmaf(a.z, a.z, a.w * a.w)));
}

// sum over the 16-lane DPP row; every lane gets the total.
__device__ inline float row16_sum(float x)
{
    int t;
    t = __builtin_amdgcn_update_dpp(0, __builtin_bit_cast(int, x), 0x121, 0xf, 0xf, true);
    x += __builtin_bit_cast(float, t);
    t = __builtin_amdgcn_update_dpp(0, __builtin_bit_cast(int, x), 0x122, 0xf, 0xf, true);
    x += __builtin_bit_cast(float, t);
    t = __builtin_amdgcn_update_dpp(0, __builtin_bit_cast(int, x), 0x124, 0xf, 0xf, true);
    x += __builtin_bit_cast(float, t);
    t = __builtin_amdgcn_update_dpp(0, __builtin_bit_cast(int, x), 0x128, 0xf, 0xf, true);
    x += __builtin_bit_cast(float, t);
    return x;
}

// ---------------- temporal row inverse-norms only ----------------
__global__ __launch_bounds__(256)
void tm_norm_kernel(const float* __restrict__ tm1, const float* __restrict__ tm2,
                    float* __restrict__ inx_tm, float* __restrict__ iny_tm)
{
    int B = blockIdx.x;
    const float* src; float* inv;
    if (B < 1024) { src = tm1; inv = inx_tm; }
    else          { B -= 1024; src = tm2; inv = iny_tm; }
    const int row  = B * 4 + (threadIdx.x >> 6);
    const int lane = threadIdx.x & 63;
    const float4* p = reinterpret_cast<const float4*>(src + (size_t)row * DDIM);
    float ss = 0.f;
#pragma unroll
    for (int c = 0; c < 3; ++c) ss += sumsq4(p[lane + 64 * c]);
#pragma unroll
    for (int off = 32; off; off >>= 1) ss += __shfl_xor(ss, off, 64);
    if (lane == 0) inv[row] = 1.0f / (sqrtf(ss) + 1e-12f);
}

// ============== spatial cost GEMM, f32 inputs + fused row norms ==============
// R16: 112-row tiles -> grid 1024 = 8 XCD * 16 batch * 2 rowtile * 4 coltile.
// Block 448 thr (7 waves), RT=1 (16 rows/wave), LDS 22.5KB single buffer,
// A-prefetch regs halved (VGPR ~70 < 73 budget for 7 waves/SIMD).
// 4 blocks/CU = 28 waves: releases the grid-bound occupancy cap of R15.
__global__ __launch_bounds__(448)
void cost_gemm_sp2(const float* __restrict__ X, const float* __restrict__ Y,
                   __bf16* __restrict__ Aout)
{
    __shared__ __bf16 lds[11264];          // A 112*64 + B 64*64 = 22,528 B
    float* ldsF = reinterpret_cast<float*>(lds);

    const int flat  = blockIdx.x;
    const int xcd   = flat & 7;
    const int s     = flat >> 3;           // 0..127
    const int b     = xcd * 16 + (s >> 3);
    const int rem   = s & 7;
    const int r0    = (rem >> 2) * 112;    // 0 or 112
    const int ct_   = rem & 3;
    const int n0    = (ct_ < 3) ? ct_ * 64 : 132;

    const int tid  = threadIdx.x;
    const int w    = tid >> 6, lane = tid & 63;
    const int q    = lane >> 4, l16 = lane & 15;
    const int srow = tid >> 3;          // 0..55
    const int sslt = tid & 7;           // 0..7

    const float* Yb = Y + (size_t)b * NSP * DDIM;

    float4 aL[2], aH[2], bL, bH, b2L, b2H;
    float ssA[2] = {0.f, 0.f};
    float ssB = 0.f, ssB2 = 0.f;

    auto LOADS = [&](int k0) {
#pragma unroll
        for (int p = 0; p < 2; ++p) {
            int gr = b * NSP + r0 + srow + 56 * p;
            gr = min(gr, BS * NSP - 1);              // clamp; masked at store
            const float* sp = X + (size_t)gr * DDIM + k0 + sslt * 8;
            aL[p] = *reinterpret_cast<const float4*>(sp);
            aH[p] = *reinterpret_cast<const float4*>(sp + 4);
        }
        {
            const float* sp = Yb + (size_t)(n0 + srow) * DDIM + k0 + sslt * 8;
            bL = *reinterpret_cast<const float4*>(sp);
            bH = *reinterpret_cast<const float4*>(sp + 4);
        }
        if (tid < 64) {
            const float* sp = Yb + (size_t)(n0 + 56 + srow) * DDIM + k0 + sslt * 8;
            b2L = *reinterpret_cast<const float4*>(sp);
            b2H = *reinterpret_cast<const float4*>(sp + 4);
        }
    };
    auto WRITES = [&]() {
#pragma unroll
        for (int p = 0; p < 2; ++p) {
            int r = srow + 56 * p;
            ssA[p] += sumsq4(aL[p]) + sumsq4(aH[p]);
            *reinterpret_cast<bf16x8*>(&lds[r * 64 + ((sslt ^ (r & 7)) << 3)]) =
                f4x2_to_bf8(aL[p], aH[p]);
        }
        {
            int r = srow;
            ssB += sumsq4(bL) + sumsq4(bH);
            *reinterpret_cast<bf16x8*>(&lds[7168 + r * 64 + ((sslt ^ (r & 7)) << 3)]) =
                f4x2_to_bf8(bL, bH);
        }
        if (tid < 64) {
            int r = 56 + srow;
            ssB2 += sumsq4(b2L) + sumsq4(b2H);
            *reinterpret_cast<bf16x8*>(&lds[7168 + r * 64 + ((sslt ^ (r & 7)) << 3)]) =
                f4x2_to_bf8(b2L, b2H);
        }
    };

    f32x4 acc[4];
#pragma unroll
    for (int j = 0; j < 4; ++j) acc[j] = f32x4{0.f, 0.f, 0.f, 0.f};

    LOADS(0);
    for (int kt = 0; kt < 12; ++kt) {
        if (kt) __syncthreads();             // prev tile fully consumed
        WRITES();
        __syncthreads();
        if (kt < 11) LOADS((kt + 1) * 64);   // covered by MFMA phase below
#pragma unroll
        for (int ks = 0; ks < 2; ++ks) {
            bf16x8 af, bf[4];
            {
                int r = w * 16 + l16;
                af = *reinterpret_cast<const bf16x8*>(
                    &lds[r * 64 + (((ks * 4 + q) ^ (r & 7)) << 3)]);
            }
#pragma unroll
            for (int ct = 0; ct < 4; ++ct) {
                int r = ct * 16 + l16;
                bf[ct] = *reinterpret_cast<const bf16x8*>(
                    &lds[7168 + r * 64 + (((ks * 4 + q) ^ (r & 7)) << 3)]);
            }
#pragma unroll
            for (int ct = 0; ct < 4; ++ct)
                acc[ct] = __builtin_amdgcn_mfma_f32_16x16x32_bf16(af, bf[ct], acc[ct], 0, 0, 0);
        }
    }
    __syncthreads();

    // ---- reduce norm partials through the (now free) LDS buffer ----
    // A rows: ldsF[row*8 + sslt] (112 rows); B rows: ldsF[896 + row*8 + sslt]
#pragma unroll
    for (int p = 0; p < 2; ++p) ldsF[(srow + 56 * p) * 8 + sslt] = ssA[p];
    ldsF[896 + srow * 8 + sslt] = ssB;
    if (tid < 64) ldsF[896 + (56 + srow) * 8 + sslt] = ssB2;
    __syncthreads();

    float ivy[4];
#pragma unroll
    for (int ct = 0; ct < 4; ++ct) {
        int jr = ct * 16 + l16;
        f32x4 s0 = *reinterpret_cast<const f32x4*>(&ldsF[896 + jr * 8]);
        f32x4 s1 = *reinterpret_cast<const f32x4*>(&ldsF[896 + jr * 8 + 4]);
        float ss = (s0.x + s0.y) + (s0.z + s0.w) + (s1.x + s1.y) + (s1.z + s1.w);
        ivy[ct] = 1.0f / (sqrtf(ss) + 1e-12f);
    }
#pragma unroll
    for (int rr = 0; rr < 4; ++rr) {
        int i = w * 16 + q * 4 + rr;
        int gi = r0 + i;
        if (gi < NSP) {
            f32x4 s0 = *reinterpret_cast<const f32x4*>(&ldsF[i * 8]);
            f32x4 s1 = *reinterpret_cast<const f32x4*>(&ldsF[i * 8 + 4]);
            float ss = (s0.x + s0.y) + (s0.z + s0.w) + (s1.x + s1.y) + (s1.z + s1.w);
            float ivx = 1.0f / (sqrtf(ss) + 1e-12f);
#pragma unroll
            for (int ct = 0; ct < 4; ++ct) {
                float cs = acc[ct][rr] * ivx * ivy[ct];
                Aout[(size_t)b * 65536 + (size_t)gi * 256 + (n0 + ct * 16 + l16)] =
                    (__bf16)__expf(2.0f * cs - 2.0f);
            }
        }
    }
}

// ---------------- temporal cost GEMM (f32 in/out) ----------------
template<int WROWS, int NWAVES, int BN, int NPTS>
__global__ __launch_bounds__(NWAVES * 64)
void cost_gemm(const float* __restrict__ X, const float* __restrict__ Y,
               const float* __restrict__ invx, const float* __restrict__ invy,
               float* __restrict__ Aout)
{
    constexpr int MT = WROWS * NWAVES;
    constexpr int CT = BN / 16;
    constexpr int RT = WROWS / 16;
    constexpr int KP = 40;
    constexpr int NTH = NWAVES * 64;
    __shared__ __bf16 As[MT][KP];
    __shared__ __bf16 Bs[BN][KP];

    const int b    = blockIdx.y;
    const int row0 = blockIdx.x * MT;
    const int tid  = threadIdx.x;
    const int w    = tid >> 6, lane = tid & 63;
    const int q    = lane >> 4, l16 = lane & 15;
    const float* Xb = X + (size_t)b * NPTS * DDIM;
    const float* Yb = Y + (size_t)b * NPTS * DDIM;

    f32x4 acc[RT][CT];
#pragma unroll
    for (int i = 0; i < RT; ++i)
#pragma unroll
        for (int j = 0; j < CT; ++j) acc[i][j] = f32x4{0.f, 0.f, 0.f, 0.f};

    for (int k0 = 0; k0 < DDIM; k0 += 32) {
        __syncthreads();
        for (int idx = tid * 4; idx < MT * 32; idx += NTH * 4) {
            int r = idx >> 5, kk = idx & 31;
            int gr = row0 + r;
            float4 v = {0.f, 0.f, 0.f, 0.f};
            if (gr < NPTS) v = *reinterpret_cast<const float4*>(Xb + (size_t)gr * DDIM + k0 + kk);
            *reinterpret_cast<ushort4*>(&As[r][kk]) = f4_to_bf4(v);
        }
        for (int idx = tid * 4; idx < BN * 32; idx += NTH * 4) {
            int r = idx >> 5, kk = idx & 31;
            float4 v = {0.f, 0.f, 0.f, 0.f};
            if (r < NPTS) v = *reinterpret_cast<const float4*>(Yb + (size_t)r * DDIM + k0 + kk);
            *reinterpret_cast<ushort4*>(&Bs[r][kk]) = f4_to_bf4(v);
        }
        __syncthreads();

        bf16x8 af[RT];
#pragma unroll
        for (int rt = 0; rt < RT; ++rt)
            af[rt] = *reinterpret_cast<const bf16x8*>(&As[w * WROWS + rt * 16 + l16][q * 8]);
#pragma unroll
        for (int ct = 0; ct < CT; ++ct) {
            bf16x8 bfr = *reinterpret_cast<const bf16x8*>(&Bs[ct * 16 + l16][q * 8]);
#pragma unroll
            for (int rt = 0; rt < RT; ++rt)
                acc[rt][ct] = __builtin_amdgcn_mfma_f32_16x16x32_bf16(af[rt], bfr, acc[rt][ct], 0, 0, 0);
        }
    }

#pragma unroll
    for (int rt = 0; rt < RT; ++rt)
#pragma unroll
        for (int ct = 0; ct < CT; ++ct)
#pragma unroll
            for (int rr = 0; rr < 4; ++rr) {
                int i = row0 + w * WROWS + rt * 16 + q * 4 + rr;
                int j = ct * 16 + l16;
                if (i < NPTS && j < NPTS) {
                    float g  = acc[rt][ct][rr];
                    float cs = g * invx[b * NPTS + i] * invy[b * NPTS + j];
                    Aout[(size_t)b * NPTS * NPTS + (size_t)i * NPTS + j] = expf(-2.0f * (1.0f - cs));
                }
            }
}

// ========== fused IPOT v6: DPP rowsum, 512 thr, A in LDS ==========
__global__ __launch_bounds__(512, 1)
void ipot_dpp(const __bf16* __restrict__ Asp, const float* __restrict__ Atm,
              float* __restrict__ out)
{
    __shared__ __bf16 Alds[224 * 256];    // 114,688 B
    __shared__ float  cpart[32 * 260];    //  33,280 B
    __shared__ float  svec[2][272];
    __shared__ float  wsum[8];

    const int B = blockIdx.x;
    if (B >= 128) {
        if (threadIdx.x >= 64) return;
        const int b = B - 128;
        const float* Ab = Atm + (size_t)b * NTM * NTM;
        const int lane = threadIdx.x;
        const int rh = lane >> 5, cj = lane & 31;
        constexpr float MIU = 1.f / NTM;
        float A[16], P[16];
#pragma unroll
        for (int k = 0; k < 16; ++k) {
            A[k] = Ab[(rh + 2 * k) * NTM + cj];
            P[k] = 1.f;
        }
        float sv = MIU;
        for (int it = 0; it < 20; ++it) {
#pragma unroll
            for (int k = 0; k < 16; ++k) {
                P[k] *= A[k];
                float acc = row16_sum(P[k] * sv);
                acc += __shfl_xor(acc, 16);
                P[k] *= MIU * __builtin_amdgcn_rcpf(acc + 1e-6f);
            }
            float cssum = 0.f;
#pragma unroll
            for (int k = 0; k < 16; ++k) cssum += P[k];
            cssum += __shfl_xor(cssum, 32);
            float sg = MIU * __builtin_amdgcn_rcpf(cssum + 1e-6f);
#pragma unroll
            for (int k = 0; k < 16; ++k) P[k] *= sg;
            sv = sg;
        }
        float acc = 0.f;
#pragma unroll
        for (int k = 0; k < 16; ++k)
            acc = fmaf(P[k], -0.5f * __logf(A[k]), acc);
        acc = row16_sum(acc);
        acc += __shfl_xor(acc, 16);
        acc += __shfl_xor(acc, 32);
        if (lane == 0) atomicAdd(out, -acc * (1.f / BS));
        return;
    }

    const int b = (B & 7) * 16 + (B >> 3);
    const __bf16* Ab = Asp + (size_t)b * 65536;
    const int tid = threadIdx.x;
    const int w = tid >> 6, lane = tid & 63;
    const int rq = lane >> 4, cl = lane & 15;
    const int g = w * 4 + rq;
    const int colbase = cl * 8;
    constexpr float MIU = 1.f / NSP;

    for (int idx = tid; idx < NSP * 32; idx += 512) {
        int r = idx >> 5, c = idx & 31;
        bf16x8 v;
#pragma unroll
        for (int i = 0; i < 8; ++i) v[i] = (__bf16)0.f;
        if (c < 25) {
            v = *reinterpret_cast<const bf16x8*>(&Ab[(size_t)r * 256 + c * 8]);
            if (c == 24) { v[4] = (__bf16)0.f; v[5] = (__bf16)0.f; v[6] = (__bf16)0.f; v[7] = (__bf16)0.f; }
        }
        *reinterpret_cast<bf16x8*>(&Alds[r * 256 + c * 8]) = v;
    }
    {
        ushort4 z = {0, 0, 0, 0};
        for (int idx = tid; idx < 28 * 64; idx += 512) {
            int r = 196 + (idx >> 6), c4 = (idx & 63) << 2;
            *reinterpret_cast<ushort4*>(&Alds[r * 256 + c4]) = z;
        }
    }
    __syncthreads();

    float P[7][16];
#pragma unroll
    for (int k = 0; k < 7; ++k)
#pragma unroll
        for (int e = 0; e < 16; ++e) P[k][e] = 1.f;

    float sr[16];
#pragma unroll
    for (int e = 0; e < 16; ++e) {
        int j = (e < 8) ? (colbase + e) : (colbase + 128 + (e - 8));
        sr[e] = (j < NSP) ? MIU : 0.f;
    }

    for (int it = 0; it < 20; ++it) {
        float cs[16];
#pragma unroll
        for (int e = 0; e < 16; ++e) cs[e] = 0.f;

#pragma unroll
        for (int k = 0; k < 7; ++k) {
            const __bf16* ap = &Alds[(g + 32 * k) * 256 + colbase];
            bf16x8 a0 = *reinterpret_cast<const bf16x8*>(ap);
            bf16x8 a1 = *reinterpret_cast<const bf16x8*>(ap + 128);
            float r0 = 0.f, r1 = 0.f;
#pragma unroll
            for (int e = 0; e < 8; ++e) {
                P[k][e] *= (float)a0[e];
                r0 = fmaf(P[k][e], sr[e], r0);
            }
#pragma unroll
            for (int e = 0; e < 8; ++e) {
                P[k][8 + e] *= (float)a1[e];
                r1 = fmaf(P[k][8 + e], sr[8 + e], r1);
            }
            float racc = row16_sum(r0 + r1);
            float delta = MIU * __builtin_amdgcn_rcpf(racc + 1e-6f);
#pragma unroll
            for (int e = 0; e < 16; ++e) {
                P[k][e] *= delta;
                cs[e] += P[k][e];
            }
        }
        {
            float* cp = &cpart[g * 260 + colbase];
            *reinterpret_cast<f32x4*>(cp)     = f32x4{cs[0], cs[1], cs[2], cs[3]};
            *reinterpret_cast<f32x4*>(cp + 4) = f32x4{cs[4], cs[5], cs[6], cs[7]};
            float* cp2 = cp + 128;
            *reinterpret_cast<f32x4*>(cp2)     = f32x4{cs[8], cs[9], cs[10], cs[11]};
            *reinterpret_cast<f32x4*>(cp2 + 4) = f32x4{cs[12], cs[13], cs[14], cs[15]};
        }
        __syncthreads();
        if (tid < 256) {
            float s0 = 0.f, s1 = 0.f, s2 = 0.f, s3 = 0.f;
#pragma unroll
            for (int gg = 0; gg < 32; gg += 4) {
                s0 += cpart[(gg + 0) * 260 + tid];
                s1 += cpart[(gg + 1) * 260 + tid];
                s2 += cpart[(gg + 2) * 260 + tid];
                s3 += cpart[(gg + 3) * 260 + tid];
            }
            float sum = (s0 + s1) + (s2 + s3);
            svec[it & 1][tid] = (tid < NSP) ? (MIU * __builtin_amdgcn_rcpf(sum + 1e-6f)) : 0.f;
        }
        __syncthreads();
        {
            const float* sv = svec[it & 1];
            f32x4 t0 = *reinterpret_cast<const f32x4*>(&sv[colbase]);
            f32x4 t1 = *reinterpret_cast<const f32x4*>(&sv[colbase + 4]);
            f32x4 t2 = *reinterpret_cast<const f32x4*>(&sv[colbase + 128]);
            f32x4 t3 = *reinterpret_cast<const f32x4*>(&sv[colbase + 132]);
            sr[0] = t0.x; sr[1] = t0.y; sr[2] = t0.z; sr[3] = t0.w;
            sr[4] = t1.x; sr[5] = t1.y; sr[6] = t1.z; sr[7] = t1.w;
            sr[8] = t2.x; sr[9] = t2.y; sr[10] = t2.z; sr[11] = t2.w;
            sr[12] = t3.x; sr[13] = t3.y; sr[14] = t3.z; sr[15] = t3.w;
        }
#pragma unroll
        for (int k = 0; k < 7; ++k)
#pragma unroll
            for (int e = 0; e < 16; ++e) P[k][e] *= sr[e];
    }

    float acc = 0.f;
#pragma unroll
    for (int k = 0; k < 7; ++k) {
        const __bf16* ap = &Alds[(g + 32 * k) * 256 + colbase];
        bf16x8 a0 = *reinterpret_cast<const bf16x8*>(ap);
        bf16x8 a1 = *reinterpret_cast<const bf16x8*>(ap + 128);
#pragma unroll
        for (int e = 0; e < 8; ++e) {
            acc = fmaf(P[k][e],     -0.5f * __logf(fmaxf((float)a0[e], 1e-30f)), acc);
            acc = fmaf(P[k][8 + e], -0.5f * __logf(fmaxf((float)a1[e], 1e-30f)), acc);
        }
    }
    acc = row16_sum(acc);
    acc += __shfl_xor(acc, 16);
    acc += __shfl_xor(acc, 32);
    if (lane == 0) wsum[w] = acc;
    __syncthreads();
    if (tid == 0) {
        float t = 0.f;
#pragma unroll
        for (int i = 0; i < 8; ++i) t += wsum[i];
        atomicAdd(out, -t * (1.f / BS));
    }
}

extern "C" void kernel_launch(void* const* d_in, const int* in_sizes, int n_in,
                              void* d_out, int out_size, void* d_ws, size_t ws_size,
                              hipStream_t stream)
{
    const float* sp1 = (const float*)d_in[0];
    const float* sp2 = (const float*)d_in[1];
    const float* tm1 = (const float*)d_in[2];
    const float* tm2 = (const float*)d_in[3];
    float* out = (float*)d_out;
    float* ws  = (float*)d_ws;

    float* inx_tm = ws;                          // 4096
    float* iny_tm = inx_tm + BS * NTM;           // 4096
    float* A_tm   = iny_tm + BS * NTM;           // 131072 f32
    __bf16* A_sp  = (__bf16*)(ws + 139264);      // 128*256*256 bf16 = 33,554,432 B

    tm_norm_kernel<<<dim3(2048), 256, 0, stream>>>(tm1, tm2, inx_tm, iny_tm);

    cost_gemm_sp2<<<dim3(1024), 448, 0, stream>>>(sp1, sp2, A_sp);

    cost_gemm<16, 2, 32, NTM><<<dim3(1, BS), 128, 0, stream>>>(tm1, tm2, inx_tm, iny_tm, A_tm);

    (void)hipMemsetAsync(d_out, 0, sizeof(float), stream);

    ipot_dpp<<<dim3(256), 512, 0, stream>>>(A_sp, A_tm, out);
}